// Round 8
// baseline (378.344 us; speedup 1.0000x reference)
//
#include <hip/hip_runtime.h>

typedef _Float16 half_t;
typedef _Float16 half8 __attribute__((ext_vector_type(8)));
typedef float f32x4 __attribute__((ext_vector_type(4)));

#define D_EMBED   1024
#define D_CROSS   768
#define N_HEADS   8
#define D_HEAD    128
#define BATCH     8
#define SEQ_Q     4096
#define SEQ_KV    77
#define M_Q       (BATCH*SEQ_Q)     /* 32768 */
#define ROWS_KV   (BATCH*SEQ_KV)    /* 616   */
#define ROWS_KV_PAD 640

// ---------------- workspace layout (bytes) ----------------
#define WS_Q     ((size_t)0)                                  // q (swizzled fp16), attn-out in place
#define WS_WQT   (WS_Q    + (size_t)M_Q*D_EMBED*2)            // Wq^T fp16 [1024][1024] swizzled
#define WS_WOT   (WS_WQT  + (size_t)D_EMBED*D_EMBED*2)        // Wo^T fp16 [1024][1024] swizzled
#define WS_WKVT  (WS_WOT  + (size_t)D_EMBED*D_EMBED*2)        // [Wk;Wv]^T fp16 [2048][768] plain
#define WS_YH    (WS_WKVT + (size_t)2*D_EMBED*D_CROSS*2)      // y fp16 padded [640][768]
#define WS_KV    (WS_YH   + (size_t)ROWS_KV_PAD*D_CROSS*2)    // kv fp16 [640][2048] plain
#define WS_BKV   (WS_KV   + (size_t)ROWS_KV_PAD*2*D_EMBED*2)  // bias concat fp32 [2048]

__device__ __forceinline__ void gload_lds16(const void* g, void* lds) {
  __builtin_amdgcn_global_load_lds(
      (const __attribute__((address_space(1))) unsigned int*)g,
      (__attribute__((address_space(3))) unsigned int*)lds, 16, 0, 0);
}
// raw barrier + scheduler fence (no vmcnt/lgkm drain)
__device__ __forceinline__ void BAR() {
  __builtin_amdgcn_s_barrier();
  __builtin_amdgcn_sched_barrier(0);
}

// ---------------- prep kernels ----------------
// dst[n][k] = (half) src[k][n]; SWZ: XOR byte bits[5:4] with (n>>1)&3 (LDS bank swizzle baked in)
template<bool SWZ>
__global__ void transpose_f32f16(const float* __restrict__ src, half_t* __restrict__ dst,
                                 int K, int N) {
  __shared__ float tile[32][33];
  int n0 = blockIdx.x * 32, k0 = blockIdx.y * 32;
  int tx = threadIdx.x, ty = threadIdx.y;
#pragma unroll
  for (int j = 0; j < 4; ++j)
    tile[ty + j*8][tx] = src[(size_t)(k0 + ty + j*8)*N + n0 + tx];
  __syncthreads();
#pragma unroll
  for (int j = 0; j < 4; ++j) {
    int n = n0 + ty + j*8, k = k0 + tx;
    size_t byte = ((size_t)n*K + k)*2;
    if (SWZ) byte ^= ((size_t)((n>>1)&3))<<4;
    *(half_t*)((char*)dst + byte) = (half_t)tile[tx][ty + j*8];
  }
}

__global__ void convert_pad_y(const float* __restrict__ y, half_t* __restrict__ yh) {
  int idx = blockIdx.x * 256 + threadIdx.x;
  int s = idx / D_CROSS;
  yh[idx] = (s < ROWS_KV) ? (half_t)y[idx] : (half_t)0.f;
}

__global__ void concat_bias(const float* __restrict__ bk, const float* __restrict__ bv,
                            float* __restrict__ bkv) {
  int i = blockIdx.x * 256 + threadIdx.x;
  bkv[i] = (i < D_EMBED) ? bk[i] : bv[i - D_EMBED];
}

// ---------------- 128x128 GEMM (R7-verified) — used for small K/V projection ----------------
__global__ __launch_bounds__(256, 3)
void gemm_kv(const half_t* __restrict__ A, const half_t* __restrict__ Bt,
             const float* __restrict__ bias, half_t* __restrict__ C,
             int M, int N, int K) {
  __shared__ half_t As[3][128*32];
  __shared__ half_t Bs[2][128*32];
  const int tid = threadIdx.x;
  const int l = tid & 63, w = tid >> 6;
  const int l4 = l & 15, lh = l >> 4;
  const int bn0 = blockIdx.x * 128, bm0 = blockIdx.y * 128;
  const int wr = w >> 1, wc = w & 1;
  const int rslot = lh << 4;             // no swizzle (plain layouts)
  f32x4 acc[4][4] = {};
  const int nk = K >> 5;
  const int srow = w*16 + (l >> 2);
  const int scol = (l & 3)*8;

  auto stageB = [&](int kt, int bb) {
    const half_t* g = Bt + (size_t)(bn0 + srow)*K + scol + kt*32;
    gload_lds16(g,                 (char*)Bs[bb] + w*1024);
    gload_lds16(g + (size_t)64*K,  (char*)Bs[bb] + 4096 + w*1024);
  };
  auto stageA = [&](int kt, int bb) {
    const half_t* g = A + (size_t)(bm0 + srow)*K + scol + kt*32;
    gload_lds16(g,                 (char*)As[bb] + w*1024);
    gload_lds16(g + (size_t)64*K,  (char*)As[bb] + 4096 + w*1024);
  };
  auto compute = [&](int ab, int bb) {
    half8 af[4], bf[4];
#pragma unroll
    for (int m = 0; m < 4; ++m)
      af[m] = *(const half8*)((const char*)As[ab] + (size_t)(wr*64 + m*16 + l4)*64 + rslot);
#pragma unroll
    for (int n = 0; n < 4; ++n)
      bf[n] = *(const half8*)((const char*)Bs[bb] + (size_t)(wc*64 + n*16 + l4)*64 + rslot);
#pragma unroll
    for (int m = 0; m < 4; ++m)
#pragma unroll
      for (int n = 0; n < 4; ++n)
        acc[m][n] = __builtin_amdgcn_mfma_f32_16x16x32_f16(af[m], bf[n], acc[m][n], 0, 0, 0);
  };

  stageA(0, 0); stageA(1, 1); stageB(0, 0);
  asm volatile("s_waitcnt vmcnt(0)" ::: "memory");
  BAR();
  int aCur = 0, aP2 = 2;
  for (int t = 0; t < nk; ++t) {
    if (t + 1 < nk) stageB(t + 1, (t + 1) & 1);
    if (t + 2 < nk) stageA(t + 2, aP2);
    compute(aCur, t & 1);
    if (t + 1 < nk) {
      if (t + 2 < nk) { asm volatile("s_waitcnt vmcnt(2)" ::: "memory"); }
      else            { asm volatile("s_waitcnt vmcnt(0)" ::: "memory"); }
      BAR();
    }
    aCur = (aCur == 2) ? 0 : aCur + 1;
    aP2  = (aP2  == 2) ? 0 : aP2  + 1;
  }

  const int cb = bn0 + wc*64, rb = bm0 + wr*64;
#pragma unroll
  for (int n = 0; n < 4; ++n) {
    const int col = cb + n*16 + l4;
    const float bvv = bias[col];
#pragma unroll
    for (int m = 0; m < 4; ++m)
#pragma unroll
      for (int j = 0; j < 4; ++j)
        C[(size_t)(rb + m*16 + lh*4 + j)*N + col] = (half_t)(acc[m][n][j] + bvv);
  }
}

// ---------------- 256x256 GEMM, 8 waves, counted-vmcnt pipeline (R7 sync logic) ----------------
// C[M,N] = A[M,K]*Bt[N,K]^T + bias. 512 thr = 8 waves (2M x 4N), wave tile 128x64,
// BK=32. LDS 5 x 16KB buffers (80KB). fp16 path: A 2-ahead (3-buf), B 1-ahead
// (2-buf); issue B(t+1) then A(t+2); end-of-iter vmcnt(2) -> {A,B}(t+1) landed,
// A(t+2) flying. AF32 path: A reg-staged (aload(t+1) early, cvt+swizzled ds_write
// after compute; its data-dep forces B(t+1) landed), B 2-ahead (3-buf).
// Bank swizzle: globals pre-swizzled (byte ^= ((row>>1)&3)<<4), staging linear,
// ds accesses XOR a per-lane-constant key. XCD-chunked block remap (grid%8==0).
template<bool AF32, bool OUTF32>
__global__ __launch_bounds__(512, 2)
void gemm256(const void* __restrict__ Av, const half_t* __restrict__ Bt,
             const float* __restrict__ bias, void* __restrict__ Cv,
             int M, int N, int K) {
  __shared__ half_t As[AF32 ? 2 : 3][256*32];   // 16 KB per buf
  __shared__ half_t Bs[AF32 ? 3 : 2][256*32];   // total 80 KB
  const int tid = threadIdx.x;
  const int l  = tid & 63;
  const int w  = tid >> 6;                      // 0..7
  const int l4 = l & 15, lh = l >> 4;

  // XCD-chunked remap: xcd = s&7 owns 64 consecutive lin slots (panel-major)
  const int s = blockIdx.x;
  const int lin = (s & 7) * ((int)gridDim.x >> 3) + (s >> 3);
  const int nbx = N >> 8;
  const int bx = lin % nbx, by = lin / nbx;
  const int bn0 = bx << 8;
  const int bm0 = by << 8;
  const int wr = w >> 2, wc = w & 3;            // 2M x 4N
  const int rslot = (lh ^ ((l4 >> 1) & 3)) << 4;

  f32x4 acc[8][4] = {};
  const int nk = K >> 5;

  // fp16 staging: 2 gload_lds/thread/tile; round r covers rows r*128 + w*16 + (l>>2)
  const int srow = w*16 + (l >> 2);
  const int scol = (l & 3)*8;

  auto stageB = [&](int kt, int bb) {
    const half_t* g = Bt + (size_t)(bn0 + srow)*K + scol + kt*32;
    gload_lds16(g,                 (char*)Bs[bb] + w*1024);
    gload_lds16(g + (size_t)128*K, (char*)Bs[bb] + 8192 + w*1024);
  };
  auto stageA16 = [&](int kt, int bb) {
    const half_t* A = (const half_t*)Av;
    const half_t* g = A + (size_t)(bm0 + srow)*K + scol + kt*32;
    gload_lds16(g,                 (char*)As[bb] + w*1024);
    gload_lds16(g + (size_t)128*K, (char*)As[bb] + 8192 + w*1024);
  };

  // AF32 reg staging: thread -> row tid>>1 (0..255), 16 floats at col (tid&1)*16
  f32x4 L0, L1, L2, L3;
  const int arow = tid >> 1;
  const int ac0  = (tid & 1) * 16;
  const int akey = (tid >> 2) & 3;              // (arow>>1)&3
  const int as0  = ((tid & 1) * 2) ^ akey;      // 16B slot of h0
  const int as1  = ((tid & 1) * 2 + 1) ^ akey;  // 16B slot of h1
  auto aload = [&](int kt) {
    const float* A = (const float*)Av;
    const float* g = A + (size_t)(bm0 + arow)*K + kt*32 + ac0;
    L0 = *(const f32x4*)g;       L1 = *(const f32x4*)(g + 4);
    L2 = *(const f32x4*)(g + 8); L3 = *(const f32x4*)(g + 12);
  };
  auto awrite = [&](int bb) {
    half8 h0, h1;
#pragma unroll
    for (int j = 0; j < 4; ++j) { h0[j] = (half_t)L0[j]; h0[j+4] = (half_t)L1[j]; }
#pragma unroll
    for (int j = 0; j < 4; ++j) { h1[j] = (half_t)L2[j]; h1[j+4] = (half_t)L3[j]; }
    char* base = (char*)As[bb] + (size_t)arow*64;
    *(half8*)(base + (as0 << 4)) = h0;
    *(half8*)(base + (as1 << 4)) = h1;
  };

  auto compute = [&](int ab, int bb) {
    half8 bf[4];
#pragma unroll
    for (int ni = 0; ni < 4; ++ni)
      bf[ni] = *(const half8*)((const char*)Bs[bb] + (size_t)(wc*64 + ni*16 + l4)*64 + rslot);
#pragma unroll
    for (int mi = 0; mi < 8; ++mi) {
      half8 af = *(const half8*)((const char*)As[ab] + (size_t)(wr*128 + mi*16 + l4)*64 + rslot);
#pragma unroll
      for (int ni = 0; ni < 4; ++ni)
        acc[mi][ni] = __builtin_amdgcn_mfma_f32_16x16x32_f16(af, bf[ni], acc[mi][ni], 0, 0, 0);
    }
  };

  if constexpr (!AF32) {
    stageA16(0, 0); stageA16(1, 1); stageB(0, 0);
    asm volatile("s_waitcnt vmcnt(0)" ::: "memory");
    BAR();
    int aCur = 0, aP2 = 2;
    for (int t = 0; t < nk; ++t) {
      if (t + 1 < nk) stageB(t + 1, (t + 1) & 1);   // B first (older in queue)
      if (t + 2 < nk) stageA16(t + 2, aP2);         // A second (left in flight)
      compute(aCur, t & 1);
      if (t + 1 < nk) {
        if (t + 2 < nk) { asm volatile("s_waitcnt vmcnt(2)" ::: "memory"); }
        else            { asm volatile("s_waitcnt vmcnt(0)" ::: "memory"); }
        BAR();
      }
      aCur = (aCur == 2) ? 0 : aCur + 1;
      aP2  = (aP2  == 2) ? 0 : aP2  + 1;
    }
  } else {
    aload(0); stageB(0, 0); stageB(1, 1);
    awrite(0);                                   // implicit wait on the 4 A-loads
    asm volatile("s_waitcnt vmcnt(2) lgkmcnt(0)" ::: "memory");  // B0 landed, B1 flying
    BAR();
    int bCur = 0, bP2 = 2;
    for (int t = 0; t < nk; ++t) {
      if (t + 1 < nk) aload(t + 1);              // issue early (T14)
      if (t + 2 < nk) stageB(t + 2, bP2);
      compute(t & 1, bCur);
      if (t + 1 < nk) {
        awrite((t + 1) & 1);                     // cvt+ds_write; forces B(t+1) landed
        asm volatile("s_waitcnt lgkmcnt(0)" ::: "memory");
        BAR();
      }
      bCur = (bCur == 2) ? 0 : bCur + 1;
      bP2  = (bP2  == 2) ? 0 : bP2  + 1;
    }
  }

  // epilogue: row = bm0 + wr*128 + mi*16 + lh*4 + j; col = bn0 + wc*64 + ni*16 + l4
  const int c_base = bn0 + wc*64;
  const int r_base = bm0 + wr*128;
#pragma unroll
  for (int ni = 0; ni < 4; ++ni) {
    const int col = c_base + ni*16 + l4;
    const float bvv = bias[col];
#pragma unroll
    for (int mi = 0; mi < 8; ++mi) {
#pragma unroll
      for (int j = 0; j < 4; ++j) {
        const int row = r_base + mi*16 + lh*4 + j;
        const float v = acc[mi][ni][j] + bvv;
        if constexpr (OUTF32) {
          ((float*)Cv)[(size_t)row*N + col] = v;
        } else {
          size_t byte = ((size_t)row*N + col)*2;
          byte ^= ((size_t)((row >> 1) & 3)) << 4;   // store q pre-swizzled
          *(half_t*)((char*)Cv + byte) = (half_t)v;
        }
      }
    }
  }
}

// ---------------- attention ----------------
// q is SWIZZLED fp16 (XOR byte[5:4] with (row>>1)&3); kv plain. (Verified R3-R7.)
__global__ __launch_bounds__(256, 2)
void attn_kernel(half_t* __restrict__ q, const half_t* __restrict__ kv) {
  __shared__ half_t K_lds[80*136];
  __shared__ half_t Vt_lds[128*104];
  __shared__ half_t P_lds[64*104];
  const int tid = threadIdx.x;
  const int l = tid & 63, w = tid >> 6;
  const int l4 = l & 15, lh = l >> 4;
  const int bh = blockIdx.y;
  const int b = bh >> 3, h = bh & 7;
  const size_t kvbase = (size_t)b*SEQ_KV*2048 + (size_t)h*D_HEAD;

  for (int i = tid; i < 80*16; i += 256) {
    int s = i >> 4, d = (i & 15) << 3;
    half8 v = {};
    if (s < SEQ_KV) v = *(const half8*)(kv + kvbase + (size_t)s*2048 + d);
    *(half8*)(K_lds + s*136 + d) = v;
  }
  for (int i = tid; i < 96*16; i += 256) {
    int s = i >> 4, d = (i & 15) << 3;
    half8 v = {};
    if (s < SEQ_KV) v = *(const half8*)(kv + kvbase + (size_t)s*2048 + 1024 + d);
#pragma unroll
    for (int j = 0; j < 8; ++j) Vt_lds[(size_t)(d + j)*104 + s] = v[j];
  }
  {
    int rr = tid >> 2, cc = 80 + (tid & 3)*4;
    *reinterpret_cast<uint2*>(P_lds + (size_t)rr*104 + cc) = make_uint2(0u, 0u);
  }
  __syncthreads();

  const int qrow0 = blockIdx.x*64 + w*16;
  const size_t qrow = (size_t)b*SEQ_Q + qrow0 + l4;
  const size_t rowbyte = qrow*2048;
  const size_t rkey = ((size_t)((l4 >> 1) & 3)) << 4;
  half8 qf[4];
#pragma unroll
  for (int kk = 0; kk < 4; ++kk) {
    size_t byte = rowbyte + (size_t)h*256 + kk*64 + lh*16;
    qf[kk] = *(const half8*)((const char*)q + (byte ^ rkey));
  }

  f32x4 sa[5] = {};
#pragma unroll
  for (int nb = 0; nb < 5; ++nb)
#pragma unroll
    for (int kk = 0; kk < 4; ++kk) {
      half8 kf = *(const half8*)(K_lds + (size_t)(nb*16 + l4)*136 + kk*32 + lh*8);
      sa[nb] = __builtin_amdgcn_mfma_f32_16x16x32_f16(qf[kk], kf, sa[nb], 0, 0, 0);
    }

  const float scale = 0.08838834764831845f;
#pragma unroll
  for (int j = 0; j < 4; ++j) {
    float pv[5];
    float mx = -1e30f;
#pragma unroll
    for (int nb = 0; nb < 5; ++nb) {
      int col = nb*16 + l4;
      float sv = (col < SEQ_KV) ? sa[nb][j]*scale : -1e30f;
      pv[nb] = sv;
      mx = fmaxf(mx, sv);
    }
    mx = fmaxf(mx, __shfl_xor(mx, 1));
    mx = fmaxf(mx, __shfl_xor(mx, 2));
    mx = fmaxf(mx, __shfl_xor(mx, 4));
    mx = fmaxf(mx, __shfl_xor(mx, 8));
    float sm = 0.f;
#pragma unroll
    for (int nb = 0; nb < 5; ++nb) { float e = __expf(pv[nb] - mx); pv[nb] = e; sm += e; }
    sm += __shfl_xor(sm, 1);
    sm += __shfl_xor(sm, 2);
    sm += __shfl_xor(sm, 4);
    sm += __shfl_xor(sm, 8);
    const float inv = 1.f / sm;
    const int prow = w*16 + lh*4 + j;
#pragma unroll
    for (int nb = 0; nb < 5; ++nb)
      P_lds[(size_t)prow*104 + nb*16 + l4] = (half_t)(pv[nb]*inv);
  }

  half8 pf[3];
#pragma unroll
  for (int kk = 0; kk < 3; ++kk)
    pf[kk] = *(const half8*)(P_lds + (size_t)(w*16 + l4)*104 + kk*32 + lh*8);
  f32x4 oa[8] = {};
#pragma unroll
  for (int nd = 0; nd < 8; ++nd)
#pragma unroll
    for (int kk = 0; kk < 3; ++kk) {
      half8 vf = *(const half8*)(Vt_lds + (size_t)(nd*16 + l4)*104 + kk*32 + lh*8);
      oa[nd] = __builtin_amdgcn_mfma_f32_16x16x32_f16(pf[kk], vf, oa[nd], 0, 0, 0);
    }
#pragma unroll
  for (int nd = 0; nd < 8; ++nd) {
#pragma unroll
    for (int j = 0; j < 4; ++j) {
      const int rl = lh*4 + j;
      const size_t row = (size_t)b*SEQ_Q + qrow0 + rl;
      size_t byte = row*2048 + (size_t)h*256 + (size_t)(nd*16 + l4)*2;
      byte ^= ((size_t)((rl >> 1) & 3)) << 4;
      *(half_t*)((char*)q + byte) = (half_t)oa[nd][j];
    }
  }
}

// ---------------- launch ----------------
extern "C" void kernel_launch(void* const* d_in, const int* in_sizes, int n_in,
                              void* d_out, int out_size, void* d_ws, size_t ws_size,
                              hipStream_t stream) {
  (void)in_sizes; (void)n_in; (void)out_size; (void)ws_size;
  const float* x  = (const float*)d_in[0];
  const float* y  = (const float*)d_in[1];
  const float* Wq = (const float*)d_in[2];
  const float* bq = (const float*)d_in[3];
  const float* Wk = (const float*)d_in[4];
  const float* bk = (const float*)d_in[5];
  const float* Wv = (const float*)d_in[6];
  const float* bv = (const float*)d_in[7];
  const float* Wo = (const float*)d_in[8];
  const float* bo = (const float*)d_in[9];

  char* ws = (char*)d_ws;
  half_t* q    = (half_t*)(ws + WS_Q);
  half_t* Wqt  = (half_t*)(ws + WS_WQT);
  half_t* Wot  = (half_t*)(ws + WS_WOT);
  half_t* Wkvt = (half_t*)(ws + WS_WKVT);
  half_t* yh   = (half_t*)(ws + WS_YH);
  half_t* kvb  = (half_t*)(ws + WS_KV);
  float*  bkv  = (float*)(ws + WS_BKV);

  dim3 tb(32, 8);
  transpose_f32f16<true ><<<dim3(32, 32), tb, 0, stream>>>(Wq, Wqt, 1024, 1024);
  transpose_f32f16<true ><<<dim3(32, 32), tb, 0, stream>>>(Wo, Wot, 1024, 1024);
  transpose_f32f16<false><<<dim3(32, 24), tb, 0, stream>>>(Wk, Wkvt, 768, 1024);
  transpose_f32f16<false><<<dim3(32, 24), tb, 0, stream>>>(Wv, Wkvt + (size_t)1024*768, 768, 1024);
  convert_pad_y<<<ROWS_KV_PAD*D_CROSS/256, 256, 0, stream>>>(y, yh);
  concat_bias<<<2*D_EMBED/256, 256, 0, stream>>>(bk, bv, bkv);

  // K/V projection: [640,768] @ [768,2048] (plain layouts, 128^2 pipelined)
  gemm_kv<<<dim3(16, 5), 256, 0, stream>>>(yh, Wkvt, bkv, kvb, ROWS_KV_PAD, 2048, 768);
  // Q projection: fp32 A reg-staged, 256^2 8-wave counted-vmcnt -> q (swizzled fp16)
  gemm256<true, false><<<512, 512, 0, stream>>>(x, Wqt, bq, q, M_Q, 1024, 1024);
  // attention (in-place over swizzled q)
  attn_kernel<<<dim3(64, 64), 256, 0, stream>>>(q, kvb);
  // O projection: fp16 A (swizzled q), 256^2 8-wave counted-vmcnt -> fp32 d_out
  gemm256<false, true><<<512, 512, 0, stream>>>(q, Wot, bo, (float*)d_out, M_Q, 1024, 1024);
}

// Round 9
// 289.468 us; speedup vs baseline: 1.3070x; 1.3070x over previous
//
#include <hip/hip_runtime.h>

typedef _Float16 half_t;
typedef _Float16 half8 __attribute__((ext_vector_type(8)));
typedef float f32x4 __attribute__((ext_vector_type(4)));

#define D_EMBED   1024
#define D_CROSS   768
#define N_HEADS   8
#define D_HEAD    128
#define BATCH     8
#define SEQ_Q     4096
#define SEQ_KV    77
#define SKV_PAD   80                    /* per-head padded kv length */
#define NKV       (N_HEADS*SKV_PAD)     /* 640: S/P columns per batch */
#define M_Q       (BATCH*SEQ_Q)         /* 32768 */

// ---------------- workspace layout (bytes) ----------------
#define WS_S     ((size_t)0)                                   // S then P in-place: [32768][640] fp16
#define WS_WQC   (WS_S    + (size_t)M_Q*NKV*2)                 // Wq cast fp16 [1024][1024] plain
#define WS_WOT   (WS_WQC  + (size_t)D_EMBED*D_EMBED*2)         // Wo^T fp16 [1024][1024] plain
#define WS_WKVT  (WS_WOT  + (size_t)D_EMBED*D_EMBED*2)         // [Wk;Wv]^T fp16 [2048][768] plain
#define WS_YH    (WS_WKVT + (size_t)2*D_EMBED*D_CROSS*2)       // y fp16 padded [8][80][768]
#define WS_KV    (WS_YH   + (size_t)BATCH*SKV_PAD*D_CROSS*2)   // kv fp16 [8*80][2048]
#define WS_BKV   (WS_KV   + (size_t)BATCH*SKV_PAD*2*D_EMBED*2) // bias concat fp32 [2048]
#define WS_BT1   (WS_BKV  + (size_t)2*D_EMBED*4)               // W1^T fp16 [8][640][1024] swizzled
#define WS_BT2   (WS_BT1  + (size_t)BATCH*NKV*D_EMBED*2)       // W2^T fp16 [8][1024][640] swizzled
#define WS_C1    (WS_BT2  + (size_t)BATCH*D_EMBED*NKV*2)       // c1 fp32 [8][640]

#define ATTN_SCALE 0.08838834764831845f  /* 1/sqrt(128) */

__device__ __forceinline__ void gload_lds16(const void* g, void* lds) {
  __builtin_amdgcn_global_load_lds(
      (const __attribute__((address_space(1))) unsigned int*)g,
      (__attribute__((address_space(3))) unsigned int*)lds, 16, 0, 0);
}
__device__ __forceinline__ void BAR() {
  __builtin_amdgcn_s_barrier();
  __builtin_amdgcn_sched_barrier(0);
}

// ---------------- prep kernels ----------------
__global__ void cast_f32_f16(const float* __restrict__ src, half_t* __restrict__ dst) {
  int i = blockIdx.x * 256 + threadIdx.x;          // each thread 8 elems
  f32x4 a = *(const f32x4*)(src + (size_t)i*8);
  f32x4 b = *(const f32x4*)(src + (size_t)i*8 + 4);
  half8 h;
#pragma unroll
  for (int j = 0; j < 4; ++j) { h[j] = (half_t)a[j]; h[j+4] = (half_t)b[j]; }
  *(half8*)(dst + (size_t)i*8) = h;
}

// dst[n][k] = (half) src[k][n]  (plain)
__global__ void transpose_f32f16(const float* __restrict__ src, half_t* __restrict__ dst,
                                 int K, int N) {
  __shared__ float tile[32][33];
  int n0 = blockIdx.x * 32, k0 = blockIdx.y * 32;
  int tx = threadIdx.x, ty = threadIdx.y;
#pragma unroll
  for (int j = 0; j < 4; ++j)
    tile[ty + j*8][tx] = src[(size_t)(k0 + ty + j*8)*N + n0 + tx];
  __syncthreads();
#pragma unroll
  for (int j = 0; j < 4; ++j)
    dst[(size_t)(n0 + ty + j*8)*K + k0 + tx] = (half_t)tile[tx][ty + j*8];
}

// y [8][77][768] fp32 -> yh [8][80][768] fp16 (pad rows zero)
__global__ void convert_pad_y(const float* __restrict__ y, half_t* __restrict__ yh) {
  int idx = blockIdx.x * 256 + threadIdx.x;        // 640*768
  int r = idx / D_CROSS, col = idx - r*D_CROSS;
  int b = r / SKV_PAD, s = r - b*SKV_PAD;
  yh[idx] = (s < SEQ_KV) ? (half_t)y[(size_t)(b*SEQ_KV + s)*D_CROSS + col] : (half_t)0.f;
}

__global__ void concat_bias(const float* __restrict__ bk, const float* __restrict__ bv,
                            float* __restrict__ bkv) {
  int i = blockIdx.x * 256 + threadIdx.x;
  bkv[i] = (i < D_EMBED) ? bk[i] : bv[i - D_EMBED];
}

// ---------------- 128x128 GEMM (R7/R8-verified) — K/V projection ----------------
__global__ __launch_bounds__(256, 3)
void gemm_kv(const half_t* __restrict__ A, const half_t* __restrict__ Bt,
             const float* __restrict__ bias, half_t* __restrict__ C,
             int M, int N, int K) {
  __shared__ half_t As[3][128*32];
  __shared__ half_t Bs[2][128*32];
  const int tid = threadIdx.x;
  const int l = tid & 63, w = tid >> 6;
  const int l4 = l & 15, lh = l >> 4;
  const int bn0 = blockIdx.x * 128, bm0 = blockIdx.y * 128;
  const int wr = w >> 1, wc = w & 1;
  const int rslot = lh << 4;
  f32x4 acc[4][4] = {};
  const int nk = K >> 5;
  const int srow = w*16 + (l >> 2);
  const int scol = (l & 3)*8;

  auto stageB = [&](int kt, int bb) {
    const half_t* g = Bt + (size_t)(bn0 + srow)*K + scol + kt*32;
    gload_lds16(g,                 (char*)Bs[bb] + w*1024);
    gload_lds16(g + (size_t)64*K,  (char*)Bs[bb] + 4096 + w*1024);
  };
  auto stageA = [&](int kt, int bb) {
    const half_t* g = A + (size_t)(bm0 + srow)*K + scol + kt*32;
    gload_lds16(g,                 (char*)As[bb] + w*1024);
    gload_lds16(g + (size_t)64*K,  (char*)As[bb] + 4096 + w*1024);
  };
  auto compute = [&](int ab, int bb) {
    half8 af[4], bf[4];
#pragma unroll
    for (int m = 0; m < 4; ++m)
      af[m] = *(const half8*)((const char*)As[ab] + (size_t)(wr*64 + m*16 + l4)*64 + rslot);
#pragma unroll
    for (int n = 0; n < 4; ++n)
      bf[n] = *(const half8*)((const char*)Bs[bb] + (size_t)(wc*64 + n*16 + l4)*64 + rslot);
#pragma unroll
    for (int m = 0; m < 4; ++m)
#pragma unroll
      for (int n = 0; n < 4; ++n)
        acc[m][n] = __builtin_amdgcn_mfma_f32_16x16x32_f16(af[m], bf[n], acc[m][n], 0, 0, 0);
  };

  stageA(0, 0); stageA(1, 1); stageB(0, 0);
  asm volatile("s_waitcnt vmcnt(0)" ::: "memory");
  BAR();
  int aCur = 0, aP2 = 2;
  for (int t = 0; t < nk; ++t) {
    if (t + 1 < nk) stageB(t + 1, (t + 1) & 1);
    if (t + 2 < nk) stageA(t + 2, aP2);
    compute(aCur, t & 1);
    if (t + 1 < nk) {
      if (t + 2 < nk) { asm volatile("s_waitcnt vmcnt(2)" ::: "memory"); }
      else            { asm volatile("s_waitcnt vmcnt(0)" ::: "memory"); }
      BAR();
    }
    aCur = (aCur == 2) ? 0 : aCur + 1;
    aP2  = (aP2  == 2) ? 0 : aP2  + 1;
  }

  const int cb = bn0 + wc*64, rb = bm0 + wr*64;
#pragma unroll
  for (int n = 0; n < 4; ++n) {
    const int col = cb + n*16 + l4;
    const float bvv = bias[col];
#pragma unroll
    for (int m = 0; m < 4; ++m)
#pragma unroll
      for (int j = 0; j < 4; ++j)
        C[(size_t)(rb + m*16 + lh*4 + j)*N + col] = (half_t)(acc[m][n][j] + bvv);
  }
}

// ---------------- builders ----------------
// Bt1[b*640 + h*80 + s][k] = scale * sum_d K[b,s,h,d] * Wq[k, h*128+d]   (swizzled store)
__global__ __launch_bounds__(256, 2)
void w1_build(const half_t* __restrict__ kvb, const half_t* __restrict__ Wqc,
              half_t* __restrict__ Bt1) {
  __shared__ half_t K_lds[80*136];
  const int blk = blockIdx.x;
  const int b = blk >> 3, h = blk & 7;
  const int tid = threadIdx.x;
  const int l = tid & 63, w = tid >> 6;
  const int l4 = l & 15, lh = l >> 4;
  for (int i = tid; i < 80*16; i += 256) {
    int s = i >> 4, d = (i & 15) << 3;
    *(half8*)(K_lds + s*136 + d) =
        *(const half8*)(kvb + (size_t)(b*SKV_PAD + s)*2048 + h*128 + d);
  }
  __syncthreads();
  for (int c = 0; c < 4; ++c) {
    f32x4 acc[5][4] = {};
#pragma unroll
    for (int kt = 0; kt < 4; ++kt) {
      half8 af[5], bf[4];
#pragma unroll
      for (int m = 0; m < 5; ++m)
        af[m] = *(const half8*)(K_lds + (size_t)(m*16 + l4)*136 + kt*32 + lh*8);
#pragma unroll
      for (int n = 0; n < 4; ++n)
        bf[n] = *(const half8*)(Wqc + (size_t)(w*256 + c*64 + n*16 + l4)*1024 + h*128 + kt*32 + lh*8);
#pragma unroll
      for (int m = 0; m < 5; ++m)
#pragma unroll
        for (int n = 0; n < 4; ++n)
          acc[m][n] = __builtin_amdgcn_mfma_f32_16x16x32_f16(af[m], bf[n], acc[m][n], 0, 0, 0);
    }
#pragma unroll
    for (int n = 0; n < 4; ++n) {
      const int colk = w*256 + c*64 + n*16 + l4;
#pragma unroll
      for (int m = 0; m < 5; ++m)
#pragma unroll
        for (int j = 0; j < 4; ++j) {
          const int srow = m*16 + lh*4 + j;
          size_t byte = (((size_t)(b*NKV + h*SKV_PAD + srow))*1024 + colk)*2;
          byte ^= ((size_t)((srow >> 1) & 3)) << 4;
          *(half_t*)((char*)Bt1 + byte) = (half_t)(acc[m][n][j]*ATTN_SCALE);
        }
    }
  }
}

// Bt2[b*1024 + n][h*80 + s] = sum_d V[b,s,h,d] * Wo[h*128+d, n]   (swizzled store)
__global__ __launch_bounds__(256, 2)
void w2_build(const half_t* __restrict__ kvb, const half_t* __restrict__ Wot,
              half_t* __restrict__ Bt2) {
  __shared__ half_t V_lds[80*136];
  const int blk = blockIdx.x;
  const int b = blk >> 3, h = blk & 7;
  const int tid = threadIdx.x;
  const int l = tid & 63, w = tid >> 6;
  const int l4 = l & 15, lh = l >> 4;
  for (int i = tid; i < 80*16; i += 256) {
    int s = i >> 4, d = (i & 15) << 3;
    *(half8*)(V_lds + s*136 + d) =
        *(const half8*)(kvb + (size_t)(b*SKV_PAD + s)*2048 + 1024 + h*128 + d);
  }
  __syncthreads();
  for (int c = 0; c < 4; ++c) {
    f32x4 acc[4][5] = {};
#pragma unroll
    for (int kt = 0; kt < 4; ++kt) {
      half8 af[4], bf[5];
#pragma unroll
      for (int m = 0; m < 4; ++m)
        af[m] = *(const half8*)(Wot + (size_t)(w*256 + c*64 + m*16 + l4)*1024 + h*128 + kt*32 + lh*8);
#pragma unroll
      for (int n = 0; n < 5; ++n)
        bf[n] = *(const half8*)(V_lds + (size_t)(n*16 + l4)*136 + kt*32 + lh*8);
#pragma unroll
      for (int m = 0; m < 4; ++m)
#pragma unroll
        for (int n = 0; n < 5; ++n)
          acc[m][n] = __builtin_amdgcn_mfma_f32_16x16x32_f16(af[m], bf[n], acc[m][n], 0, 0, 0);
    }
#pragma unroll
    for (int m = 0; m < 4; ++m) {
#pragma unroll
      for (int j = 0; j < 4; ++j) {
        const int nrow = w*256 + c*64 + m*16 + lh*4 + j;
#pragma unroll
        for (int n = 0; n < 5; ++n) {
          const int scol = n*16 + l4;
          size_t byte = (((size_t)(b*1024 + nrow))*NKV + h*SKV_PAD + scol)*2;
          byte ^= ((size_t)((nrow >> 1) & 3)) << 4;
          *(half_t*)((char*)Bt2 + byte) = (half_t)acc[m][n][j];
        }
      }
    }
  }
}

// c1[b*640 + h*80 + s] = scale * sum_d bq[h*128+d] * K[b,s,h,d]
__global__ void c1_build(const half_t* __restrict__ kvb, const float* __restrict__ bq,
                         float* __restrict__ c1) {
  int idx = blockIdx.x * 256 + threadIdx.x;        // 5120
  int b = idx / NKV, n = idx - b*NKV;
  int h = n / SKV_PAD, s = n - h*SKV_PAD;
  const half_t* kp = kvb + (size_t)(b*SKV_PAD + s)*2048 + h*128;
  float acc = 0.f;
#pragma unroll 8
  for (int d = 0; d < 128; ++d) acc += bq[h*128 + d] * (float)kp[d];
  c1[idx] = acc * ATTN_SCALE;
}

// ---------------- big GEMM: C[M,N] = A[M,K] * Bt_b[N,K]^T + bias_b[N] ----------------
// R7-verified counted-vmcnt pipeline; per-batch B/bias (batch = by>>5);
// batch-per-XCD remap (grid = NBX*256, chunk = grid/8 = one batch's blocks).
// B pre-swizzled in global (byte ^= ((row>>1)&3)<<4); A plain (both fp32-reg path
// and fp16 gload path); A-side LDS reads plain (R4: conflicts ~free here).
template<bool AF32, bool OUTF32, int NBX>
__global__ __launch_bounds__(256, 3)
void gemm_bt(const void* __restrict__ Av, const half_t* __restrict__ BtAll,
             const float* __restrict__ biasAll, void* __restrict__ Cv,
             int M, int N, int K, int btBatchStride, int biasBatchStride) {
  __shared__ half_t As[AF32 ? 2 : 3][128*32];
  __shared__ half_t Bs[AF32 ? 3 : 2][128*32];
  const int tid = threadIdx.x;
  const int l  = tid & 63;
  const int w  = tid >> 6;
  const int l4 = l & 15, lh = l >> 4;

  const int chunk = (int)gridDim.x >> 3;           // blocks per XCD = one batch
  const int sb = blockIdx.x;
  const int lin = (sb & 7)*chunk + (sb >> 3);
  const int bx = lin % NBX;
  const int by = lin / NBX;
  const int b  = by >> 5;                          // 32 M-blocks per batch
  const half_t* Bt  = BtAll  + (size_t)b*btBatchStride;
  const float* bias = biasAll + (size_t)b*biasBatchStride;

  const int bn0 = bx * 128;
  const int bm0 = by * 128;
  const int wr = w >> 1, wc = w & 1;
  const int aslot = lh << 4;                           // A plain
  const int bslot = (lh ^ ((l4 >> 1) & 3)) << 4;       // B swizzled

  f32x4 acc[4][4] = {};
  const int nk = K >> 5;
  const int srow = w*16 + (l >> 2);
  const int scol = (l & 3)*8;

  auto stageB = [&](int kt, int bb) {
    const half_t* g = Bt + (size_t)(bn0 + srow)*K + scol + kt*32;
    gload_lds16(g,                (char*)Bs[bb] + w*1024);
    gload_lds16(g + (size_t)64*K, (char*)Bs[bb] + 4096 + w*1024);
  };
  auto stageA16 = [&](int kt, int bb) {
    const half_t* A = (const half_t*)Av;
    const half_t* g = A + (size_t)(bm0 + srow)*K + scol + kt*32;
    gload_lds16(g,                (char*)As[bb] + w*1024);
    gload_lds16(g + (size_t)64*K, (char*)As[bb] + 4096 + w*1024);
  };

  f32x4 L0, L1, L2, L3;
  const int arow = tid >> 2;
  const int ac0  = (tid & 3) * 8;
  const int wslot = (tid & 3) << 4;                    // plain
  auto aload = [&](int kt) {
    const float* A = (const float*)Av;
    const float* g0 = A + (size_t)(bm0 + arow)*K + kt*32 + ac0;
    const float* g1 = A + (size_t)(bm0 + 64 + arow)*K + kt*32 + ac0;
    L0 = *(const f32x4*)g0; L1 = *(const f32x4*)(g0 + 4);
    L2 = *(const f32x4*)g1; L3 = *(const f32x4*)(g1 + 4);
  };
  auto awrite = [&](int bb) {
    half8 h0, h1;
#pragma unroll
    for (int j = 0; j < 4; ++j) { h0[j] = (half_t)L0[j]; h0[j+4] = (half_t)L1[j]; }
#pragma unroll
    for (int j = 0; j < 4; ++j) { h1[j] = (half_t)L2[j]; h1[j+4] = (half_t)L3[j]; }
    *(half8*)((char*)As[bb] + (size_t)arow*64 + wslot)        = h0;
    *(half8*)((char*)As[bb] + (size_t)(64 + arow)*64 + wslot) = h1;
  };

  auto compute = [&](int ab, int bb) {
    half8 af[4], bf[4];
#pragma unroll
    for (int m = 0; m < 4; ++m)
      af[m] = *(const half8*)((const char*)As[ab] + (size_t)(wr*64 + m*16 + l4)*64 + aslot);
#pragma unroll
    for (int n = 0; n < 4; ++n)
      bf[n] = *(const half8*)((const char*)Bs[bb] + (size_t)(wc*64 + n*16 + l4)*64 + bslot);
#pragma unroll
    for (int m = 0; m < 4; ++m)
#pragma unroll
      for (int n = 0; n < 4; ++n)
        acc[m][n] = __builtin_amdgcn_mfma_f32_16x16x32_f16(af[m], bf[n], acc[m][n], 0, 0, 0);
  };

  if constexpr (!AF32) {
    stageA16(0, 0); stageA16(1, 1); stageB(0, 0);
    asm volatile("s_waitcnt vmcnt(0)" ::: "memory");
    BAR();
    int aCur = 0, aP2 = 2;
    for (int t = 0; t < nk; ++t) {
      if (t + 1 < nk) stageB(t + 1, (t + 1) & 1);
      if (t + 2 < nk) stageA16(t + 2, aP2);
      compute(aCur, t & 1);
      if (t + 1 < nk) {
        if (t + 2 < nk) { asm volatile("s_waitcnt vmcnt(2)" ::: "memory"); }
        else            { asm volatile("s_waitcnt vmcnt(0)" ::: "memory"); }
        BAR();
      }
      aCur = (aCur == 2) ? 0 : aCur + 1;
      aP2  = (aP2  == 2) ? 0 : aP2  + 1;
    }
  } else {
    aload(0); stageB(0, 0); stageB(1, 1);
    awrite(0);
    asm volatile("s_waitcnt vmcnt(2) lgkmcnt(0)" ::: "memory");
    BAR();
    int bCur = 0, bP2 = 2;
    for (int t = 0; t < nk; ++t) {
      if (t + 1 < nk) aload(t + 1);
      if (t + 2 < nk) stageB(t + 2, bP2);
      compute(t & 1, bCur);
      if (t + 1 < nk) {
        awrite((t + 1) & 1);
        asm volatile("s_waitcnt lgkmcnt(0)" ::: "memory");
        BAR();
      }
      bCur = (bCur == 2) ? 0 : bCur + 1;
      bP2  = (bP2  == 2) ? 0 : bP2  + 1;
    }
  }

  const int c_base = bn0 + wc*64;
  const int r_base = bm0 + wr*64;
#pragma unroll
  for (int n = 0; n < 4; ++n) {
    const int col = c_base + n*16 + l4;
    const float bvv = bias[col];
#pragma unroll
    for (int m = 0; m < 4; ++m) {
#pragma unroll
      for (int j = 0; j < 4; ++j) {
        const int row = r_base + m*16 + lh*4 + j;
        const float v = acc[m][n][j] + bvv;
        if constexpr (OUTF32) ((float*)Cv)[(size_t)row*N + col] = v;
        else                  ((half_t*)Cv)[(size_t)row*N + col] = (half_t)v;
      }
    }
  }
}

// ---------------- softmax (in-place over S): per (row, head) group of 80 (77 valid) ----------------
__global__ __launch_bounds__(256, 4)
void softmax_inplace(half_t* __restrict__ S) {
  const int gid = blockIdx.x * 256 + threadIdx.x;   // 32768*8
  const int row = gid >> 3, h = gid & 7;
  half_t* p = S + (size_t)row*NKV + h*SKV_PAD;
  half8 v[10];
#pragma unroll
  for (int i = 0; i < 10; ++i) v[i] = *(const half8*)(p + i*8);
  float mx = -1e30f;
#pragma unroll
  for (int i = 0; i < 10; ++i)
#pragma unroll
    for (int j = 0; j < 8; ++j) {
      if (i*8 + j < SEQ_KV) mx = fmaxf(mx, (float)v[i][j]);
    }
  float sm = 0.f;
#pragma unroll
  for (int i = 0; i < 10; ++i) {
    half8 t = v[i];
#pragma unroll
    for (int j = 0; j < 8; ++j) {
      float e = (i*8 + j < SEQ_KV) ? __expf((float)t[j] - mx) : 0.f;
      sm += e;
      t[j] = (half_t)e;
    }
    v[i] = t;
  }
  const float inv = 1.f / sm;
#pragma unroll
  for (int i = 0; i < 10; ++i) {
    half8 t = v[i];
#pragma unroll
    for (int j = 0; j < 8; ++j) t[j] = (half_t)((float)t[j] * inv);
    *(half8*)(p + i*8) = t;
  }
}

// ---------------- launch ----------------
extern "C" void kernel_launch(void* const* d_in, const int* in_sizes, int n_in,
                              void* d_out, int out_size, void* d_ws, size_t ws_size,
                              hipStream_t stream) {
  (void)in_sizes; (void)n_in; (void)out_size; (void)ws_size;
  const float* x  = (const float*)d_in[0];
  const float* y  = (const float*)d_in[1];
  const float* Wq = (const float*)d_in[2];
  const float* bq = (const float*)d_in[3];
  const float* Wk = (const float*)d_in[4];
  const float* bk = (const float*)d_in[5];
  const float* Wv = (const float*)d_in[6];
  const float* bv = (const float*)d_in[7];
  const float* Wo = (const float*)d_in[8];
  const float* bo = (const float*)d_in[9];

  char* ws = (char*)d_ws;
  half_t* S    = (half_t*)(ws + WS_S);
  half_t* Wqc  = (half_t*)(ws + WS_WQC);
  half_t* Wot  = (half_t*)(ws + WS_WOT);
  half_t* Wkvt = (half_t*)(ws + WS_WKVT);
  half_t* yh   = (half_t*)(ws + WS_YH);
  half_t* kvb  = (half_t*)(ws + WS_KV);
  float*  bkv  = (float*)(ws + WS_BKV);
  half_t* Bt1  = (half_t*)(ws + WS_BT1);
  half_t* Bt2  = (half_t*)(ws + WS_BT2);
  float*  c1   = (float*)(ws + WS_C1);

  dim3 tb(32, 8);
  cast_f32_f16<<<512, 256, 0, stream>>>(Wq, Wqc);                       // Wq fp16 plain [k][e]
  transpose_f32f16<<<dim3(32, 32), tb, 0, stream>>>(Wo, Wot, 1024, 1024); // Wo^T plain [n][k]
  transpose_f32f16<<<dim3(32, 24), tb, 0, stream>>>(Wk, Wkvt, 768, 1024);
  transpose_f32f16<<<dim3(32, 24), tb, 0, stream>>>(Wv, Wkvt + (size_t)1024*768, 768, 1024);
  convert_pad_y<<<BATCH*SKV_PAD*D_CROSS/256, 256, 0, stream>>>(y, yh);
  concat_bias<<<2*D_EMBED/256, 256, 0, stream>>>(bk, bv, bkv);

  // K/V projection: [640,768] @ [768,2048] -> kvb (rows b*80+s; pad rows = bias, masked later)
  gemm_kv<<<dim3(16, 5), 256, 0, stream>>>(yh, Wkvt, bkv, kvb, BATCH*SKV_PAD, 2048, 768);

  // folded-weight builders (tiny)
  c1_build<<<BATCH*NKV/256, 256, 0, stream>>>(kvb, bq, c1);
  w1_build<<<BATCH*N_HEADS, 256, 0, stream>>>(kvb, Wqc, Bt1);
  w2_build<<<BATCH*N_HEADS, 256, 0, stream>>>(kvb, Wot, Bt2);

  // S = x @ W1[b] + c1[b]  (fp32 A reg-staged): M=32768, N=640, K=1024
  gemm_bt<true, false, 5><<<1280, 256, 0, stream>>>(
      x, Bt1, c1, S, M_Q, NKV, 1024, NKV*1024, NKV);

  // P = softmax(S) per (row, head), in place
  softmax_inplace<<<M_Q*N_HEADS/256, 256, 0, stream>>>(S);

  // out = P @ W2[b] + bo : M=32768, N=1024, K=640 -> fp32 d_out
  gemm_bt<false, true, 8><<<2048, 256, 0, stream>>>(
      S, Bt2, bo, (float*)d_out, M_Q, 1024, NKV, 1024*NKV, 0);
}